// Round 3
// baseline (900.886 us; speedup 1.0000x reference)
//
#include <hip/hip_runtime.h>
#include <hip/hip_fp16.h>
#include <math.h>

#define NN      100000
#define EE      1600000
#define DIN     128
#define CC      16
#define NITERS  5
#define NBLKS   100000               // 16-edge mfma blocks
#define UU      4                    // mfma blocks per wave
#define GRID_E  (NBLKS / (UU * 4))   // 6250 blocks of 256 (4 waves)
#define NEGLOGC (-2.772588722239781f)
#define FPSCALE 1048576.0f           // 2^20 fixed-point scale (agg)
#define FPINV   (1.0f / 1048576.0f)

#if __has_builtin(__builtin_amdgcn_mfma_f32_16x16x16bf16_1k)
#define USE_1K 1
#else
#define USE_1K 0
#endif

typedef float f4  __attribute__((ext_vector_type(4)));
typedef float v4f __attribute__((ext_vector_type(4)));
typedef short v4s __attribute__((ext_vector_type(4)));
typedef unsigned int u4v __attribute__((ext_vector_type(4)));
typedef unsigned long long ull;

// ---------------------------------------------------------------------------
// helpers: fp16 / bf16 <-> f32
// ---------------------------------------------------------------------------
__device__ __forceinline__ unsigned short f2h(float f) {
    return __half_as_ushort(__float2half(f));
}
__device__ __forceinline__ float h2f(unsigned short u) {
    return __half2float(__ushort_as_half(u));
}
__device__ __forceinline__ unsigned int pack_h(float lo, float hi) {
    return (unsigned int)f2h(lo) | ((unsigned int)f2h(hi) << 16);
}
__device__ __forceinline__ unsigned short f2bf(float f) {
    unsigned int u = __float_as_uint(f);
    unsigned int r = u + 0x7fffu + ((u >> 16) & 1u);   // round-nearest-even
    return (unsigned short)(r >> 16);
}

// ---------------------------------------------------------------------------
// fused setup: M = sigmoid(10*param) (+ row sums at M[256..271]);
// logb0 = log_softmax(x@W+b); aggA = 0.   grid = 6250 x 256 (covers NN*CC)
// ---------------------------------------------------------------------------
__global__ __launch_bounds__(256) void k_setup(
    const float* __restrict__ x, const float* __restrict__ W,
    const float* __restrict__ b, const float* __restrict__ param,
    float* __restrict__ M, float* __restrict__ logb0,
    unsigned int* __restrict__ aggA)
{
    if (blockIdx.x == 0) {
        if (threadIdx.x < CC * (CC + 1) / 2) {
            int i = threadIdx.x;
            int r = 0;
            while ((r + 1) * (r + 2) / 2 <= i) ++r;
            int c = i - r * (r + 1) / 2;
            float z = param[i] * 10.0f;
            float s = 1.0f / (1.0f + __expf(-z));
            M[r * CC + c] = s;
            if (r != c) M[c * CC + r] = s;
        }
        __syncthreads();                       // block-0-local barrier
        if (threadIdx.x < CC) {                // row sums for the T shortcut
            float s = 0.f;
            for (int c = 0; c < CC; ++c) s += M[threadIdx.x * CC + c];
            M[256 + threadIdx.x] = s;
        }
    }

    int idx = blockIdx.x * 256 + threadIdx.x;
    aggA[idx] = 0u;

    int node = idx >> 4;
    int cls  = idx & 15;
    const f4* xr4 = (const f4*)(x + (long)node * DIN);
    float acc = b[cls];
#pragma unroll 8
    for (int k4 = 0; k4 < DIN / 4; ++k4) {
        f4 xv = __builtin_nontemporal_load(xr4 + k4);   // x streamed once
        acc = fmaf(xv.x, W[(4 * k4 + 0) * CC + cls], acc);
        acc = fmaf(xv.y, W[(4 * k4 + 1) * CC + cls], acc);
        acc = fmaf(xv.z, W[(4 * k4 + 2) * CC + cls], acc);
        acc = fmaf(xv.w, W[(4 * k4 + 3) * CC + cls], acc);
    }
    float m = acc;
    for (int off = 8; off; off >>= 1) m = fmaxf(m, __shfl_xor(m, off, 16));
    float s = __expf(acc - m);
    for (int off = 8; off; off >>= 1) s += __shfl_xor(s, off, 16);
    logb0[idx] = acc - m - __logf(s);
}

// ---------------------------------------------------------------------------
// Fused edge kernel, swapped-operand MFMA layout (HW-verified in round 2).
//
// Lane (q,m): q = lane>>4 (k/class quad), m = lane&15 (edge within block).
// Per 16-edge block:
//   - belief of src(m) formed ON THE FLY: v = logb0[src] - FPINV*aggprev[src];
//     only the row-max is subtracted (uniform class shift cancels exactly in
//     the normalized message; max-shift guards exp underflow).
//   - e = exp(v - mx - mo);  mo = reverse message (fp16 u64, one coalesced
//     load at lane index m^1) or -logC on iter 0.
//   - T shortcut: dot(e, rowsum(M)) + 2 width-64 shuffles -> lane-local logT.
//   - D = mfma(M_as_A, e_as_B): D[i] = unnorm msg[edge m][class 4q+i].
//   - msg out: ONE u64 nontemporal store per lane (4 fp16), layout
//     msg8[blk*64 + q*16 + m]; next iter reads at m^1 (pair = reverse edge).
//   - dst(m) = src(m^1) -> one shfl_xor, no edst load at all.
//   - agg: 2 packed u64 fixed-point atomics, own lane (no packing shuffles).
//   - triple-buffered agg: read PREV, atomically build CUR, zero NEXT
//     (disjoint buffers; dispatch boundary orders zero vs next iter's atomics)
// ---------------------------------------------------------------------------
template <bool RD_MSG, bool RD_AGG, bool WR_MSG, bool ZERO>
__global__ __launch_bounds__(256) void k_edges_f(
    const int* __restrict__ esrc, const float* __restrict__ logb0,
    const float* __restrict__ Mg, const unsigned int* __restrict__ aggprev,
    ull* __restrict__ aggcur, unsigned int* __restrict__ aggnext,
    ull* __restrict__ msg8)
{
    const int lane = threadIdx.x & 63;
    const int wid  = blockIdx.x * 4 + (threadIdx.x >> 6);
    const int m    = lane & 15;
    const int q    = lane >> 4;

    if (ZERO)   // 6250*256 == NN*CC exactly: zero next iteration's agg buffer
        __builtin_nontemporal_store(0u, aggnext + blockIdx.x * 256 + threadIdx.x);

#if USE_1K
    // A-operand fragment: A[row=m][k=4q+j] = M[m][4q+j] (M symmetric)
    v4s mfrag;
#pragma unroll
    for (int j = 0; j < 4; ++j)
        mfrag[j] = (short)f2bf(Mg[m * CC + 4 * q + j]);
#endif
    f4 rs = *(const f4*)(Mg + 256 + 4 * q);    // rowsums for k = 4q..4q+3

    // ---- phase 1: independent chain heads ----
    int srcv[UU];
    ull mw[UU];
#pragma unroll
    for (int u = 0; u < UU; ++u) {
        const long blk = (long)wid * UU + u;
        srcv[u] = __builtin_nontemporal_load(esrc + blk * 16 + m);
        if (RD_MSG)
            mw[u] = __builtin_nontemporal_load(msg8 + blk * 64 + q * 16 + (m ^ 1));
    }
    // ---- phase 2: dependent gathers, still before any compute ----
    f4  lb[UU];
    u4v ag[UU];
#pragma unroll
    for (int u = 0; u < UU; ++u) {
        lb[u] = *(const f4*)(logb0 + (long)srcv[u] * CC + 4 * q);
        if (RD_AGG)
            ag[u] = *(const u4v*)(aggprev + (long)srcv[u] * CC + 4 * q);
    }

    // ---- phase 3: compute (UU independent chains in flight) ----
#pragma unroll
    for (int u = 0; u < UU; ++u) {
        const long blk = (long)wid * UU + u;

        // on-the-fly belief (un-normalized; only max-shifted)
        float v0 = lb[u].x, v1 = lb[u].y, v2 = lb[u].z, v3 = lb[u].w;
        if (RD_AGG) {
            v0 = fmaf(-(float)ag[u][0], FPINV, v0);
            v1 = fmaf(-(float)ag[u][1], FPINV, v1);
            v2 = fmaf(-(float)ag[u][2], FPINV, v2);
            v3 = fmaf(-(float)ag[u][3], FPINV, v3);
        }
        float mx = fmaxf(fmaxf(v0, v1), fmaxf(v2, v3));
        mx = fmaxf(mx, __shfl_xor(mx, 16, 64));
        mx = fmaxf(mx, __shfl_xor(mx, 32, 64));

        float mv0 = NEGLOGC, mv1 = NEGLOGC, mv2 = NEGLOGC, mv3 = NEGLOGC;
        if (RD_MSG) {
            mv0 = h2f((unsigned short)(mw[u] & 0xffffu));
            mv1 = h2f((unsigned short)((mw[u] >> 16) & 0xffffu));
            mv2 = h2f((unsigned short)((mw[u] >> 32) & 0xffffu));
            mv3 = h2f((unsigned short)(mw[u] >> 48));
        }

        float e0 = __expf(v0 - mx - mv0);   // t = belief[src] - msg[reverse]
        float e1 = __expf(v1 - mx - mv1);
        float e2 = __expf(v2 - mx - mv2);
        float e3 = __expf(v3 - mx - mv3);

        float Tm = e0 * rs.x;
        Tm = fmaf(e1, rs.y, Tm);
        Tm = fmaf(e2, rs.z, Tm);
        Tm = fmaf(e3, rs.w, Tm);
        Tm += __shfl_xor(Tm, 16, 64);
        Tm += __shfl_xor(Tm, 32, 64);
        float lT = __logf(Tm);             // log T[edge m], lane-local

        float D0, D1, D2, D3;
#if USE_1K
        v4s a;
        a[0] = (short)f2bf(e0); a[1] = (short)f2bf(e1);
        a[2] = (short)f2bf(e2); a[3] = (short)f2bf(e3);
        v4f acc = {0.f, 0.f, 0.f, 0.f};
        // swapped operands: D[row=class 4q+i][col=edge m]
        v4f D = __builtin_amdgcn_mfma_f32_16x16x16bf16_1k(mfrag, a, acc, 0, 0, 0);
        D0 = D[0]; D1 = D[1]; D2 = D[2]; D3 = D[3];
#else
        // fallback: cross-quad broadcast + scalar dot (same lane layout)
        float ee[4] = {e0, e1, e2, e3};
        float g1[4], g2[4], g3[4];
#pragma unroll
        for (int j = 0; j < 4; ++j) {
            g1[j] = __shfl_xor(ee[j], 16, 64);
            g2[j] = __shfl_xor(ee[j], 32, 64);
            g3[j] = __shfl_xor(ee[j], 48, 64);
        }
        float Dv[4];
#pragma unroll
        for (int i = 0; i < 4; ++i) {
            const float* Mr = Mg + (4 * q + i) * CC;
            float d = 0.f;
#pragma unroll
            for (int j = 0; j < 4; ++j) {
                d = fmaf(Mr[4 * q + j],       ee[j], d);
                d = fmaf(Mr[4 * (q ^ 1) + j], g1[j], d);
                d = fmaf(Mr[4 * (q ^ 2) + j], g2[j], d);
                d = fmaf(Mr[4 * (q ^ 3) + j], g3[j], d);
            }
            Dv[i] = d;
        }
        D0 = Dv[0]; D1 = Dv[1]; D2 = Dv[2]; D3 = Dv[3];
#endif
        // normalized log-message for edge m, classes 4q..4q+3
        float n0 = __logf(D0) - lT;
        float n1 = __logf(D1) - lT;
        float n2 = __logf(D2) - lT;
        float n3 = __logf(D3) - lT;

        if (WR_MSG) {
            ull w = (ull)pack_h(n0, n1) | ((ull)pack_h(n2, n3) << 32);
            __builtin_nontemporal_store(w, msg8 + blk * 64 + q * 16 + m);
        }

        // dst(edge m) = src(edge m^1): pairs are reciprocal and adjacent
        int dstv = __shfl_xor(srcv[u], 1, 16);

        unsigned int q0 = (unsigned int)(fmaxf(-n0, 0.f) * FPSCALE + 0.5f);
        unsigned int q1 = (unsigned int)(fmaxf(-n1, 0.f) * FPSCALE + 0.5f);
        unsigned int q2 = (unsigned int)(fmaxf(-n2, 0.f) * FPSCALE + 0.5f);
        unsigned int q3 = (unsigned int)(fmaxf(-n3, 0.f) * FPSCALE + 0.5f);
        atomicAdd(&aggcur[(long)dstv * 8 + 2 * q],     (ull)q0 | ((ull)q1 << 32));
        atomicAdd(&aggcur[(long)dstv * 8 + 2 * q + 1], (ull)q2 | ((ull)q3 << 32));
    }
}

// ---------------------------------------------------------------------------
// final: out = log_normalize(logb0 - FPINV*agg)  (no reset needed)
// ---------------------------------------------------------------------------
__global__ __launch_bounds__(256) void k_update(
    const float* __restrict__ logb0, const unsigned int* __restrict__ agg32,
    float* __restrict__ out)
{
    int idx = blockIdx.x * blockDim.x + threadIdx.x;
    unsigned int q = agg32[idx];
    float v = fmaf(-(float)q, FPINV, logb0[idx]);
    float m = v;
    for (int off = 8; off; off >>= 1) m = fmaxf(m, __shfl_xor(m, off, 16));
    float s = __expf(v - m);
    for (int off = 8; off; off >>= 1) s += __shfl_xor(s, off, 16);
    out[idx] = v - m - __logf(s);
}

// ---------------------------------------------------------------------------
extern "C" void kernel_launch(void* const* d_in, const int* in_sizes, int n_in,
                              void* d_out, int out_size, void* d_ws, size_t ws_size,
                              hipStream_t stream)
{
    const float* x     = (const float*)d_in[0];
    const float* W     = (const float*)d_in[1];
    const float* b     = (const float*)d_in[2];
    const float* param = (const float*)d_in[3];
    const int*   eidx  = (const int*)d_in[4];
    const int*   esrc  = eidx;                 // edst derived via pair shuffle

    float* ws    = (float*)d_ws;
    float* M     = ws;                         // 256 + 16 rowsums (pad 288)
    float* logb0 = M     + 288;                // N*C f32
    unsigned int* aggA = (unsigned int*)(logb0 + (long)NN * CC);  // N*C u32
    unsigned int* aggB = aggA + (long)NN * CC;
    unsigned int* aggC = aggB + (long)NN * CC;
    ull*          msg8 = (ull*)(aggC + (long)NN * CC);  // NBLKS*64 u64 (8B-aligned)
    float* outp  = (float*)d_out;

    k_setup<<<NN * CC / 256, 256, 0, stream>>>(x, W, b, param, M, logb0, aggA);

    // iteration rotation over {A,B,C}: (read, write, zero)
    // it1: (-,A,B)  it2: (A,B,C)  it3: (B,C,A)  it4: (C,A,B)  it5: (A,B,-)
    k_edges_f<false, false, true, true><<<GRID_E, 256, 0, stream>>>(
        esrc, logb0, M, aggA, (ull*)aggA, aggB, msg8);
    k_edges_f<true, true, true, true><<<GRID_E, 256, 0, stream>>>(
        esrc, logb0, M, aggA, (ull*)aggB, aggC, msg8);
    k_edges_f<true, true, true, true><<<GRID_E, 256, 0, stream>>>(
        esrc, logb0, M, aggB, (ull*)aggC, aggA, msg8);
    k_edges_f<true, true, true, true><<<GRID_E, 256, 0, stream>>>(
        esrc, logb0, M, aggC, (ull*)aggA, aggB, msg8);
    k_edges_f<true, true, false, false><<<GRID_E, 256, 0, stream>>>(
        esrc, logb0, M, aggA, (ull*)aggB, aggC, msg8);

    k_update<<<NN * CC / 256, 256, 0, stream>>>(logb0, aggB, outp);
}